// Round 2
// baseline (624.929 us; speedup 1.0000x reference)
//
#include <hip/hip_runtime.h>
#include <hip/hip_bf16.h>
#include <stdint.h>

// Key space: ((b*512 + x)*512 + y)*512 + z, b in {0,1} -> 2*512^3 = 2^28 keys.
#define KEYSPACE   (1u << 28)
#define NWORDS     (KEYSPACE / 32u)      // 8,388,608 u32 words (32 MB bitmap)
#define GROUP_W    8u                    // words per rank-base group (256 bits)
#define NGROUPS    (NWORDS / GROUP_W)    // 1,048,576 groups
#define NSCANBLK   (NGROUPS / 1024u)     // 1024 scan blocks (1024 groups each)

__device__ __forceinline__ uint32_t encode4(int4 c) {
    return ((((uint32_t)c.x * 512u + (uint32_t)c.y) * 512u + (uint32_t)c.z) * 512u) + (uint32_t)c.w;
}

__device__ __forceinline__ uint32_t popc8(uint4 a, uint4 b) {
    return __popc(a.x) + __popc(a.y) + __popc(a.z) + __popc(a.w)
         + __popc(b.x) + __popc(b.y) + __popc(b.z) + __popc(b.w);
}

// Mark union bitmap from x keys.
__global__ __launch_bounds__(256) void mark_x(const int* __restrict__ xC,
                                              uint32_t* __restrict__ union_bm, int Nx) {
    int i = blockIdx.x * blockDim.x + threadIdx.x;
    if (i >= Nx) return;
    int4 c = reinterpret_cast<const int4*>(xC)[i];
    uint32_t k = encode4(c);
    atomicOr(&union_bm[k >> 5], 1u << (k & 31u));
}

// Mark union bitmap + "m present with score>0.5" bitmap from m keys.
__global__ __launch_bounds__(256) void mark_m(const int* __restrict__ mC,
                                              const float* __restrict__ mF,
                                              uint32_t* __restrict__ union_bm,
                                              uint32_t* __restrict__ mgood_bm, int Nm) {
    int i = blockIdx.x * blockDim.x + threadIdx.x;
    if (i >= Nm) return;
    int4 c = reinterpret_cast<const int4*>(mC)[i];
    uint32_t k = encode4(c);
    atomicOr(&union_bm[k >> 5], 1u << (k & 31u));
    if (mF[i] > 0.5f) atomicOr(&mgood_bm[k >> 5], 1u << (k & 31u));
}

// Fused popcount + block-level exclusive scan.
// Each block covers 1024 groups (= 8192 bitmap words = 32 KB); thread t owns
// groups [blk*1024 + 4t, +4). P[] gets per-group exclusive prefix within the
// block; B[blk] gets the block total.
__global__ __launch_bounds__(256) void scan_blocks(const uint32_t* __restrict__ bm,
                                                   uint32_t* __restrict__ P,
                                                   uint32_t* __restrict__ B) {
    __shared__ uint32_t sdata[256];
    int t = threadIdx.x;
    uint32_t blk = blockIdx.x;
    size_t g0 = (size_t)blk * 1024u + (uint32_t)t * 4u;       // first group owned
    const uint4* p = reinterpret_cast<const uint4*>(bm) + g0 * 2u;
    uint32_t c0 = popc8(p[0], p[1]);
    uint32_t c1 = popc8(p[2], p[3]);
    uint32_t c2 = popc8(p[4], p[5]);
    uint32_t c3 = popc8(p[6], p[7]);
    uint32_t s = c0 + c1 + c2 + c3;
    sdata[t] = s;
    __syncthreads();
    for (int off = 1; off < 256; off <<= 1) {
        uint32_t tmp = (t >= off) ? sdata[t - off] : 0u;
        __syncthreads();
        sdata[t] += tmp;
        __syncthreads();
    }
    uint32_t ex = sdata[t] - s;  // exclusive prefix of this thread's 4 groups
    uint4 o;
    o.x = ex;
    o.y = ex + c0;
    o.z = ex + c0 + c1;
    o.w = ex + c0 + c1 + c2;
    reinterpret_cast<uint4*>(P)[blk * 256u + t] = o;
    if (t == 255) B[blk] = sdata[255];
}

// Single-block exclusive scan of the 1024 block totals.
__global__ __launch_bounds__(1024) void scan_top(const uint32_t* __restrict__ B,
                                                 uint32_t* __restrict__ Boff) {
    __shared__ uint32_t sdata[1024];
    int t = threadIdx.x;
    uint32_t v = B[t];
    sdata[t] = v;
    __syncthreads();
    for (int off = 1; off < 1024; off <<= 1) {
        uint32_t tmp = (t >= off) ? sdata[t - off] : 0u;
        __syncthreads();
        sdata[t] += tmp;
        __syncthreads();
    }
    Boff[t] = sdata[t] - v;  // exclusive
}

// Scatter surviving x rows to their union-rank row in the output.
__global__ __launch_bounds__(256) void scatter_rows(const int* __restrict__ xC,
                                                    const float* __restrict__ xF,
                                                    const uint32_t* __restrict__ union_bm,
                                                    const uint32_t* __restrict__ mgood_bm,
                                                    const uint32_t* __restrict__ P,
                                                    const uint32_t* __restrict__ Boff,
                                                    float* __restrict__ out, int Nx) {
    int i = blockIdx.x * blockDim.x + threadIdx.x;
    if (i >= Nx) return;
    int4 c = reinterpret_cast<const int4*>(xC)[i];
    uint32_t k = encode4(c);
    uint32_t w = k >> 5;
    if (!((mgood_bm[w] >> (k & 31u)) & 1u)) return;  // needs m present & score>0.5

    const float4* f = reinterpret_cast<const float4*>(xF + (size_t)i * 16u);
    float4 f0 = f[0], f1 = f[1], f2 = f[2], f3 = f[3];
    bool any =
        (f0.x > 0.f) | (f0.y > 0.f) | (f0.z > 0.f) | (f0.w > 0.f) |
        (f1.x > 0.f) | (f1.y > 0.f) | (f1.z > 0.f) | (f1.w > 0.f) |
        (f2.x > 0.f) | (f2.y > 0.f) | (f2.z > 0.f) | (f2.w > 0.f) |
        (f3.x > 0.f) | (f3.y > 0.f) | (f3.z > 0.f) | (f3.w > 0.f);
    if (!any) return;

    uint32_t g = w >> 3;  // group index
    uint32_t r = Boff[g >> 10] + P[g];
    for (uint32_t j = g * GROUP_W; j < w; ++j) r += __popc(union_bm[j]);
    r += __popc(union_bm[w] & ((1u << (k & 31u)) - 1u));

    float4* o = reinterpret_cast<float4*>(out + (size_t)r * 16u);
    o[0] = f0; o[1] = f1; o[2] = f2; o[3] = f3;
}

extern "C" void kernel_launch(void* const* d_in, const int* in_sizes, int n_in,
                              void* d_out, int out_size, void* d_ws, size_t ws_size,
                              hipStream_t stream) {
    const int* xC = (const int*)d_in[0];
    const float* xF = (const float*)d_in[1];
    const int* mC = (const int*)d_in[2];
    const float* mF = (const float*)d_in[3];
    float* out = (float*)d_out;

    int Nx = in_sizes[1] / 16;
    int Nm = in_sizes[3];

    // Workspace layout (bytes):
    //   [0, 32M)       union bitmap
    //   [32M, 64M)     mgood bitmap
    //   [64M, 68M)     P    (per-group exclusive scan, 1M u32)
    //   [68M, +4K)     B    (block sums, 1024 u32)
    //   [68M+4K, +4K)  Boff (exclusive block offsets)
    uint8_t* ws = (uint8_t*)d_ws;
    uint32_t* union_bm = (uint32_t*)(ws);
    uint32_t* mgood_bm = (uint32_t*)(ws + (size_t)32 * 1024 * 1024);
    uint32_t* P        = (uint32_t*)(ws + (size_t)64 * 1024 * 1024);
    uint32_t* B        = (uint32_t*)(ws + (size_t)68 * 1024 * 1024);
    uint32_t* Boff     = (uint32_t*)(ws + (size_t)68 * 1024 * 1024 + 4096);

    // Zero bitmaps and output (harness poisons with 0xAA before every call).
    hipMemsetAsync(union_bm, 0, (size_t)64 * 1024 * 1024, stream);
    hipMemsetAsync(out, 0, (size_t)out_size * sizeof(float), stream);

    int blk = 256;
    mark_x<<<(Nx + blk - 1) / blk, blk, 0, stream>>>(xC, union_bm, Nx);
    mark_m<<<(Nm + blk - 1) / blk, blk, 0, stream>>>(mC, mF, union_bm, mgood_bm, Nm);
    scan_blocks<<<NSCANBLK, 256, 0, stream>>>(union_bm, P, B);
    scan_top<<<1, 1024, 0, stream>>>(B, Boff);
    scatter_rows<<<(Nx + blk - 1) / blk, blk, 0, stream>>>(xC, xF, union_bm, mgood_bm,
                                                           P, Boff, out, Nx);
}

// Round 3
// 594.863 us; speedup vs baseline: 1.0505x; 1.0505x over previous
//
#include <hip/hip_runtime.h>
#include <hip/hip_bf16.h>
#include <stdint.h>

// Key space: ((b*512 + x)*512 + y)*512 + z, b in {0,1} -> 2*512^3 = 2^28 keys.
// Interleaved 2-bit bitmap: word w holds 16 keys; key k -> word k>>4,
// bit pair at 2*(k&15): bit0 = union membership, bit1 = (in m) & (m_F > 0.5).
#define KEYSPACE   (1u << 28)
#define NWORDS     (KEYSPACE / 16u)       // 16,777,216 u32 words (64 MB)
#define GROUP_W    16u                    // words per group = 256 keys = 64 B line
#define NGROUPS    (NWORDS / GROUP_W)     // 1,048,576 groups
#define NSCANBLK   (NGROUPS / 1024u)      // 1024 scan blocks
#define UMASK      0x55555555u            // union bits (even positions)

__device__ __forceinline__ uint32_t encode4(int4 c) {
    return ((((uint32_t)c.x * 512u + (uint32_t)c.y) * 512u + (uint32_t)c.z) * 512u) + (uint32_t)c.w;
}

// Fused mark: threads [0,Nx) mark x keys (union bit), threads [Nx, Nx+Nm)
// mark m keys (union bit + mgood bit). Nx is a multiple of 64 so waves never
// straddle the split.
__global__ __launch_bounds__(256) void mark_all(const int* __restrict__ xC,
                                                const int* __restrict__ mC,
                                                const float* __restrict__ mF,
                                                uint32_t* __restrict__ BM,
                                                int Nx, int Nm) {
    int i = blockIdx.x * blockDim.x + threadIdx.x;
    if (i < Nx) {
        int4 c = reinterpret_cast<const int4*>(xC)[i];
        uint32_t k = encode4(c);
        atomicOr(&BM[k >> 4], 1u << ((k & 15u) * 2u));
    } else {
        int j = i - Nx;
        if (j >= Nm) return;
        int4 c = reinterpret_cast<const int4*>(mC)[j];
        uint32_t k = encode4(c);
        uint32_t bits = (mF[j] > 0.5f) ? 3u : 1u;
        atomicOr(&BM[k >> 4], bits << ((k & 15u) * 2u));
    }
}

// Fused popcount(union bits) + block-level exclusive scan.
// Block covers 1024 groups (= 64 KB bitmap); thread t owns 4 groups
// (4 cachelines, 16 uint4 loads). P[g] = within-block exclusive prefix;
// B[blk] = block total.
__global__ __launch_bounds__(256) void scan_blocks(const uint32_t* __restrict__ BM,
                                                   uint32_t* __restrict__ P,
                                                   uint32_t* __restrict__ B) {
    __shared__ uint32_t sdata[256];
    int t = threadIdx.x;
    uint32_t blk = blockIdx.x;
    size_t g0 = (size_t)blk * 1024u + (uint32_t)t * 4u;  // first group owned
    const uint4* p = reinterpret_cast<const uint4*>(BM) + g0 * 4u;
    uint32_t cg[4];
#pragma unroll
    for (int q = 0; q < 4; ++q) {
        uint4 a = p[q * 4 + 0], b = p[q * 4 + 1], c = p[q * 4 + 2], d = p[q * 4 + 3];
        cg[q] = __popc(a.x & UMASK) + __popc(a.y & UMASK) + __popc(a.z & UMASK) + __popc(a.w & UMASK)
              + __popc(b.x & UMASK) + __popc(b.y & UMASK) + __popc(b.z & UMASK) + __popc(b.w & UMASK)
              + __popc(c.x & UMASK) + __popc(c.y & UMASK) + __popc(c.z & UMASK) + __popc(c.w & UMASK)
              + __popc(d.x & UMASK) + __popc(d.y & UMASK) + __popc(d.z & UMASK) + __popc(d.w & UMASK);
    }
    uint32_t s = cg[0] + cg[1] + cg[2] + cg[3];
    sdata[t] = s;
    __syncthreads();
    for (int off = 1; off < 256; off <<= 1) {
        uint32_t tmp = (t >= off) ? sdata[t - off] : 0u;
        __syncthreads();
        sdata[t] += tmp;
        __syncthreads();
    }
    uint32_t ex = sdata[t] - s;
    uint4 o;
    o.x = ex;
    o.y = ex + cg[0];
    o.z = ex + cg[0] + cg[1];
    o.w = ex + cg[0] + cg[1] + cg[2];
    reinterpret_cast<uint4*>(P)[blk * 256u + t] = o;
    if (t == 255) B[blk] = sdata[255];
}

// Single-block exclusive scan of the 1024 block totals.
__global__ __launch_bounds__(1024) void scan_top(const uint32_t* __restrict__ B,
                                                 uint32_t* __restrict__ Boff) {
    __shared__ uint32_t sdata[1024];
    int t = threadIdx.x;
    uint32_t v = B[t];
    sdata[t] = v;
    __syncthreads();
    for (int off = 1; off < 1024; off <<= 1) {
        uint32_t tmp = (t >= off) ? sdata[t - off] : 0u;
        __syncthreads();
        sdata[t] += tmp;
        __syncthreads();
    }
    Boff[t] = sdata[t] - v;  // exclusive
}

// Scatter surviving x rows to their union-rank row in the output.
// One random cacheline read (BM word's line) serves the mgood test AND the
// entire rank walk (group == one 64B line).
__global__ __launch_bounds__(256) void scatter_rows(const int* __restrict__ xC,
                                                    const float* __restrict__ xF,
                                                    const uint32_t* __restrict__ BM,
                                                    const uint32_t* __restrict__ P,
                                                    const uint32_t* __restrict__ Boff,
                                                    float* __restrict__ out, int Nx) {
    int i = blockIdx.x * blockDim.x + threadIdx.x;
    if (i >= Nx) return;
    int4 c = reinterpret_cast<const int4*>(xC)[i];
    uint32_t k = encode4(c);
    uint32_t w = k >> 4;
    uint32_t j2 = (k & 15u) * 2u;
    uint32_t word = BM[w];
    if (!((word >> (j2 + 1u)) & 1u)) return;  // mgood bit: m present & score>0.5

    const float4* f = reinterpret_cast<const float4*>(xF + (size_t)i * 16u);
    float4 f0 = f[0], f1 = f[1], f2 = f[2], f3 = f[3];
    bool any =
        (f0.x > 0.f) | (f0.y > 0.f) | (f0.z > 0.f) | (f0.w > 0.f) |
        (f1.x > 0.f) | (f1.y > 0.f) | (f1.z > 0.f) | (f1.w > 0.f) |
        (f2.x > 0.f) | (f2.y > 0.f) | (f2.z > 0.f) | (f2.w > 0.f) |
        (f3.x > 0.f) | (f3.y > 0.f) | (f3.z > 0.f) | (f3.w > 0.f);
    if (!any) return;

    uint32_t g = w >> 4;  // group = 16 words = one cacheline
    uint32_t r = Boff[g >> 10] + P[g];
    for (uint32_t q = g << 4; q < w; ++q) r += __popc(BM[q] & UMASK);  // same line: L1 hits
    r += __popc(word & UMASK & ((1u << j2) - 1u));

    float4* o = reinterpret_cast<float4*>(out + (size_t)r * 16u);
    o[0] = f0; o[1] = f1; o[2] = f2; o[3] = f3;
}

extern "C" void kernel_launch(void* const* d_in, const int* in_sizes, int n_in,
                              void* d_out, int out_size, void* d_ws, size_t ws_size,
                              hipStream_t stream) {
    const int* xC = (const int*)d_in[0];
    const float* xF = (const float*)d_in[1];
    const int* mC = (const int*)d_in[2];
    const float* mF = (const float*)d_in[3];
    float* out = (float*)d_out;

    int Nx = in_sizes[1] / 16;
    int Nm = in_sizes[3];

    // Workspace layout (bytes):
    //   [0, 64M)       BM   (interleaved 2-bit bitmap)
    //   [64M, 68M)     P    (per-group exclusive scan, 1M u32)
    //   [68M, +4K)     B    (block sums, 1024 u32)
    //   [68M+4K, +4K)  Boff (exclusive block offsets)
    uint8_t* ws = (uint8_t*)d_ws;
    uint32_t* BM   = (uint32_t*)(ws);
    uint32_t* P    = (uint32_t*)(ws + (size_t)64 * 1024 * 1024);
    uint32_t* B    = (uint32_t*)(ws + (size_t)68 * 1024 * 1024);
    uint32_t* Boff = (uint32_t*)(ws + (size_t)68 * 1024 * 1024 + 4096);

    hipMemsetAsync(BM, 0, (size_t)64 * 1024 * 1024, stream);
    hipMemsetAsync(out, 0, (size_t)out_size * sizeof(float), stream);

    int blk = 256;
    int total = Nx + Nm;
    mark_all<<<(total + blk - 1) / blk, blk, 0, stream>>>(xC, mC, mF, BM, Nx, Nm);
    scan_blocks<<<NSCANBLK, 256, 0, stream>>>(BM, P, B);
    scan_top<<<1, 1024, 0, stream>>>(B, Boff);
    scatter_rows<<<(Nx + blk - 1) / blk, blk, 0, stream>>>(xC, xF, BM, P, Boff, out, Nx);
}

// Round 6
// 547.333 us; speedup vs baseline: 1.1418x; 1.0868x over previous
//
#include <hip/hip_runtime.h>
#include <hip/hip_bf16.h>
#include <stdint.h>

// Key space: ((b*512 + x)*512 + y)*512 + z, b in {0,1} -> 2*512^3 = 2^28 keys.
// Bucketed rank: bucket = key >> 17 (2048 buckets); each bucket's 2^17-key
// presence bitmap lives ONLY in LDS (32 KB), 2 bits/key interleaved:
// bit0 = union membership, bit1 = (in m) & (m_F > 0.5).
#define KEYSPACE     (1u << 28)
#define NBUCKET      2048u
#define BUCKET_KEYS  (KEYSPACE / NBUCKET)    // 131072 keys per bucket
#define BUCKET_WORDS (BUCKET_KEYS / 16u)     // 8192 words = 32 KB LDS bitmap
#define BUCKET_CAP   4096u                   // entries per bucket (avg ~1950)
#define EPB          16384                   // entries per phase-1 block
#define UMASK        0x55555555u             // union bits (even positions)
#define RECS_CAP     1024u                   // survivor records per bucket (avg ~244)

__device__ __forceinline__ uint32_t encode4(int4 c) {
    return ((((uint32_t)c.x * 512u + (uint32_t)c.y) * 512u + (uint32_t)c.z) * 512u) + (uint32_t)c.w;
}

// Phase 1: bin entries into per-bucket arrays. Streaming reads, LDS histogram,
// one reserve-atomic per (block,bucket), LDS cursors.
// Entry: .x = low17 key-offset | mgood<<17 | isx<<18 ; .y = x row index.
__global__ __launch_bounds__(256) void bin_keys(const int* __restrict__ xC,
                                                const int* __restrict__ mC,
                                                const float* __restrict__ mF,
                                                uint2* __restrict__ barr,
                                                uint32_t* __restrict__ bcnt,
                                                int Nx, int Nm) {
    __shared__ uint32_t hist[NBUCKET];  // 8 KB, reused as cursor in pass B
    __shared__ uint32_t base[NBUCKET];  // 8 KB
    int t = threadIdx.x;
    int total = Nx + Nm;
    int start = blockIdx.x * EPB;
    int end = min(start + EPB, total);

    for (int q = t; q < (int)NBUCKET; q += 256) hist[q] = 0u;
    __syncthreads();

    // pass A: histogram
    for (int e = start + t; e < end; e += 256) {
        uint32_t k = (e < Nx) ? encode4(reinterpret_cast<const int4*>(xC)[e])
                              : encode4(reinterpret_cast<const int4*>(mC)[e - Nx]);
        atomicAdd(&hist[k >> 17], 1u);
    }
    __syncthreads();

    // block-level reserve
    for (int q = t; q < (int)NBUCKET; q += 256) {
        uint32_t h = hist[q];
        base[q] = h ? atomicAdd(&bcnt[q], h) : 0u;
        hist[q] = 0u;  // becomes cursor
    }
    __syncthreads();

    // pass B: scatter payloads (chunk is L2-hot from pass A)
    for (int e = start + t; e < end; e += 256) {
        uint32_t k; uint2 pl;
        if (e < Nx) {
            k = encode4(reinterpret_cast<const int4*>(xC)[e]);
            pl.x = (k & (BUCKET_KEYS - 1u)) | (1u << 18);
            pl.y = (uint32_t)e;
        } else {
            int j = e - Nx;
            k = encode4(reinterpret_cast<const int4*>(mC)[j]);
            pl.x = (k & (BUCKET_KEYS - 1u)) | ((mF[j] > 0.5f) ? (1u << 17) : 0u);
            pl.y = 0u;
        }
        uint32_t b = k >> 17;
        uint32_t pos = base[b] + atomicAdd(&hist[b], 1u);
        barr[(size_t)b * BUCKET_CAP + pos] = pl;
    }
}

// Phase 2: one block per bucket. Build the 32 KB bitmap in LDS, popcount+scan
// group prefixes (group = 256 keys) in LDS, then rank each surviving x entry
// (mgood bit set) ENTIRELY in LDS and emit a compact record
// (.x = x row, .y = bucket<<17 | local_rank). Btot[b] = bucket union count.
__global__ __launch_bounds__(256) void build_bucket(const uint2* __restrict__ barr,
                                                    const uint32_t* __restrict__ bcnt,
                                                    uint2* __restrict__ records,
                                                    uint32_t* __restrict__ rcount,
                                                    uint32_t* __restrict__ Btot) {
    __shared__ uint32_t bmp[BUCKET_WORDS];  // 32 KB
    __shared__ uint32_t gpre[512];          // per-group exclusive prefix
    __shared__ uint32_t sdata[256];
    __shared__ uint2 recs[RECS_CAP];        // 8 KB
    __shared__ uint32_t nrec, rbase;
    int t = threadIdx.x;
    uint32_t b = blockIdx.x;

    {
        uint4 z = make_uint4(0u, 0u, 0u, 0u);
        uint4* bz = reinterpret_cast<uint4*>(bmp);
        for (int q = t; q < (int)(BUCKET_WORDS / 4u); q += 256) bz[q] = z;
    }
    __syncthreads();

    uint32_t n = bcnt[b];
    const uint2* ba = barr + (size_t)b * BUCKET_CAP;

    // pass 1: build bitmap with LDS atomics
    for (uint32_t e = t; e < n; e += 256u) {
        uint32_t pl = ba[e].x;
        uint32_t off = pl & (BUCKET_KEYS - 1u);
        uint32_t bits = 1u | (((pl >> 17) & 1u) << 1);
        atomicOr(&bmp[off >> 4], bits << ((off & 15u) * 2u));
    }
    __syncthreads();

    // per-group popcount (512 groups, 2 per thread) + block scan
    uint32_t c0 = 0u, c1 = 0u;
    {
        const uint32_t* w0 = bmp + (2 * t) * 16;
        const uint32_t* w1 = bmp + (2 * t + 1) * 16;
#pragma unroll
        for (int q = 0; q < 16; ++q) c0 += __popc(w0[q] & UMASK);
#pragma unroll
        for (int q = 0; q < 16; ++q) c1 += __popc(w1[q] & UMASK);
    }
    uint32_t s = c0 + c1;
    sdata[t] = s;
    __syncthreads();
    for (int off = 1; off < 256; off <<= 1) {
        uint32_t tmp = (t >= off) ? sdata[t - off] : 0u;
        __syncthreads();
        sdata[t] += tmp;
        __syncthreads();
    }
    uint32_t ex = sdata[t] - s;
    gpre[2 * t] = ex;
    gpre[2 * t + 1] = ex + c0;
    if (t == 255) Btot[b] = sdata[255];
    if (t == 0) nrec = 0u;
    __syncthreads();

    // pass 2: rank surviving x entries in LDS, append records
    for (uint32_t e = t; e < n; e += 256u) {
        uint2 pe = ba[e];
        if (!(pe.x & (1u << 18))) continue;  // x entries only
        uint32_t off = pe.x & (BUCKET_KEYS - 1u);
        uint32_t w = off >> 4;
        uint32_t j2 = (off & 15u) * 2u;
        uint32_t word = bmp[w];
        if (!((word >> (j2 + 1u)) & 1u)) continue;  // mgood: m present & >0.5
        uint32_t g = off >> 8;
        uint32_t r = gpre[g];
        for (uint32_t q = g << 4; q < w; ++q) r += __popc(bmp[q] & UMASK);
        r += __popc(word & UMASK & ((1u << j2) - 1u));
        uint32_t pos = atomicAdd(&nrec, 1u);
        if (pos < RECS_CAP) recs[pos] = make_uint2(pe.y, (b << 17) | r);
    }
    __syncthreads();

    if (t == 0) rbase = atomicAdd(rcount, min(nrec, RECS_CAP));
    __syncthreads();
    uint32_t n2 = min(nrec, RECS_CAP);
    for (uint32_t q = t; q < n2; q += 256u) records[rbase + q] = recs[q];
}

// Exclusive scan of 2048 bucket totals (one block, 1024 threads x 2).
__global__ __launch_bounds__(1024) void scan_top(const uint32_t* __restrict__ Btot,
                                                 uint32_t* __restrict__ Boff) {
    __shared__ uint32_t sdata[1024];
    int t = threadIdx.x;
    uint32_t v0 = Btot[2 * t], v1 = Btot[2 * t + 1];
    uint32_t s = v0 + v1;
    sdata[t] = s;
    __syncthreads();
    for (int off = 1; off < 1024; off <<= 1) {
        uint32_t tmp = (t >= off) ? sdata[t - off] : 0u;
        __syncthreads();
        sdata[t] += tmp;
        __syncthreads();
    }
    uint32_t ex = sdata[t] - s;
    Boff[2 * t] = ex;
    Boff[2 * t + 1] = ex + v0;
}

// Final gather: record -> out[Boff[bucket] + local_rank] = xF[row] (if any>0).
__global__ __launch_bounds__(256) void gather_rows(const uint2* __restrict__ records,
                                                   const uint32_t* __restrict__ rcount,
                                                   const uint32_t* __restrict__ Boff,
                                                   const float* __restrict__ xF,
                                                   float* __restrict__ out) {
    uint32_t i = blockIdx.x * blockDim.x + threadIdx.x;
    if (i >= *rcount) return;
    uint2 rec = records[i];
    uint32_t row = rec.x;
    uint32_t r = Boff[rec.y >> 17] + (rec.y & (BUCKET_KEYS - 1u));

    const float4* f = reinterpret_cast<const float4*>(xF + (size_t)row * 16u);
    float4 f0 = f[0], f1 = f[1], f2 = f[2], f3 = f[3];
    bool any =
        (f0.x > 0.f) | (f0.y > 0.f) | (f0.z > 0.f) | (f0.w > 0.f) |
        (f1.x > 0.f) | (f1.y > 0.f) | (f1.z > 0.f) | (f1.w > 0.f) |
        (f2.x > 0.f) | (f2.y > 0.f) | (f2.z > 0.f) | (f2.w > 0.f) |
        (f3.x > 0.f) | (f3.y > 0.f) | (f3.z > 0.f) | (f3.w > 0.f);
    if (!any) return;

    float4* o = reinterpret_cast<float4*>(out + (size_t)r * 16u);
    o[0] = f0; o[1] = f1; o[2] = f2; o[3] = f3;
}

extern "C" void kernel_launch(void* const* d_in, const int* in_sizes, int n_in,
                              void* d_out, int out_size, void* d_ws, size_t ws_size,
                              hipStream_t stream) {
    const int* xC = (const int*)d_in[0];
    const float* xF = (const float*)d_in[1];
    const int* mC = (const int*)d_in[2];
    const float* mF = (const float*)d_in[3];
    float* out = (float*)d_out;

    int Nx = in_sizes[1] / 16;
    int Nm = in_sizes[3];
    int total = Nx + Nm;

    // Workspace layout (bytes):
    //   [0, 64M)        barr    (2048 buckets x 4096 x uint2)
    //   [64M, 80M)      records (up to 2M uint2)
    //   [80M, +8K)      bcnt  (2048 u32)  } zeroed together
    //   [80M+8K, +4)    rcount (1 u32)    }
    //   [80M+12K, +8K)  Btot
    //   [80M+20K, +8K)  Boff
    uint8_t* ws = (uint8_t*)d_ws;
    uint2*    barr    = (uint2*)(ws);
    uint2*    records = (uint2*)(ws + (size_t)64 * 1024 * 1024);
    uint32_t* bcnt    = (uint32_t*)(ws + (size_t)80 * 1024 * 1024);
    uint32_t* rcount  = (uint32_t*)(ws + (size_t)80 * 1024 * 1024 + 8192);
    uint32_t* Btot    = (uint32_t*)(ws + (size_t)80 * 1024 * 1024 + 12288);
    uint32_t* Boff    = (uint32_t*)(ws + (size_t)80 * 1024 * 1024 + 20480);

    hipMemsetAsync(out, 0, (size_t)out_size * sizeof(float), stream);
    hipMemsetAsync(bcnt, 0, 8192 + 4, stream);  // bcnt + rcount

    bin_keys<<<(total + EPB - 1) / EPB, 256, 0, stream>>>(xC, mC, mF, barr, bcnt, Nx, Nm);
    build_bucket<<<NBUCKET, 256, 0, stream>>>(barr, bcnt, records, rcount, Btot);
    scan_top<<<1, 1024, 0, stream>>>(Btot, Boff);
    gather_rows<<<(Nx + 255) / 256, 256, 0, stream>>>(records, rcount, Boff, xF, out);
}